// Round 13
// baseline (1022.313 us; speedup 1.0000x reference)
//
#include <hip/hip_runtime.h>

typedef unsigned int u32;
typedef unsigned short u16;
typedef unsigned long long u64;
typedef float floatx4 __attribute__((ext_vector_type(4)));
typedef int int32x4 __attribute__((ext_vector_type(4)));
typedef __bf16 bf16x8 __attribute__((ext_vector_type(8)));

#define DEV __device__ __forceinline__
#define LOG2E 1.4426950408889634f

DEV u16 f2bf(float f){
  u32 u = __builtin_bit_cast(u32, f);
  u += 0x7FFFu + ((u >> 16) & 1u);
  return (u16)(u >> 16);
}
DEV float bf2f(u16 h){ u32 u = ((u32)h) << 16; return __builtin_bit_cast(float, u); }
DEV u16 f2h_bits(float f){ return __builtin_bit_cast(u16, (_Float16)f); }
DEV float h_bits2f(u16 h){ return (float)__builtin_bit_cast(_Float16, h); }
// fast transcendentals, guaranteed single-instruction
DEV float exp2n(float x){ float r; asm("v_exp_f32 %0, -%1" : "=v"(r) : "v"(x)); return r; }      // 2^-x
DEV float rcp_(float x){ float r; asm("v_rcp_f32 %0, %1" : "=v"(r) : "v"(x)); return r; }
// LDS-only barrier: orders ds ops across waves WITHOUT draining vmcnt (prefetch loads stay in flight).
DEV void bar_lds(){
  __builtin_amdgcn_sched_barrier(0);
  asm volatile("s_waitcnt lgkmcnt(0)" ::: "memory");
  __builtin_amdgcn_s_barrier();
  __builtin_amdgcn_sched_barrier(0);
}

// ---------------- prep kernels ----------------

__global__ __launch_bounds__(256) void conv_bf16_k(const float* __restrict__ src, u16* __restrict__ dst, int n){
  for (int i = blockIdx.x * 256 + threadIdx.x; i < n; i += gridDim.x * 256)
    dst[i] = f2bf(src[i]);
}

// Wt[n][k] (n = dir*1280 + g*256 + h, k = i), bf16; biasWU[n] = (bW+bU)*log2e (log2-domain gates)
__global__ __launch_bounds__(256) void prep_wt_k(const float* __restrict__ Wf, const float* __restrict__ Wb,
                                                 const float* __restrict__ bWf, const float* __restrict__ bWb,
                                                 const float* __restrict__ bUf, const float* __restrict__ bUb,
                                                 u16* __restrict__ Wt, float* __restrict__ biasWU){
  int idx = blockIdx.x * 256 + threadIdx.x;
  if (idx >= 2560 * 256) return;
  int n = idx >> 8, k = idx & 255;
  int dir = n / 1280, rr = n - dir * 1280, g = rr >> 8, hc = rr & 255;
  const float* W = dir ? Wb : Wf;
  Wt[idx] = f2bf(W[(g * 256 + k) * 256 + hc]);
  if (k == 0)
    biasWU[n] = ((dir ? bWb : bWf)[g * 256 + hc] + (dir ? bUb : bUf)[g * 256 + hc]) * LOG2E;
}

// U -> i8 MFMA B-fragments + per-column scales (scaled by log2e).
__global__ __launch_bounds__(256) void prep_uq(const float* __restrict__ Uf, const float* __restrict__ Ub,
                                               signed char* __restrict__ ufr, float* __restrict__ cs){
  int colid = blockIdx.x;              // dir*1280 + g*256 + j
  int dir = colid / 1280; int rr = colid - dir * 1280; int g = rr >> 8; int j = rr & 255;
  int k = threadIdx.x;
  const float* U = dir ? Ub : Uf;
  float v = U[((size_t)g * 256 + k) * 256 + j];
  __shared__ float red[256];
  red[k] = fabsf(v); __syncthreads();
  for (int s = 128; s > 0; s >>= 1){ if (k < s) red[k] = fmaxf(red[k], red[k + s]); __syncthreads(); }
  float s = red[0];
  float q = (s > 0.f) ? 127.f / s : 0.f;
  int iq = (int)rintf(v * q);
  int jb = j >> 4, l15 = j & 15;
  int w = jb & 7, jbsel = jb >> 3;
  int c = jbsel * 5 + g;
  int ks = k >> 6, lsub = (k >> 4) & 3, e = k & 15;
  int lane = lsub * 16 + l15;
  ufr[((((size_t)(dir * 8 + w) * 10 + c) * 4 + ks) * 64 + lane) * 16 + e] = (signed char)iq;
  if (k == 0) cs[((size_t)(dir * 8 + w) * 10 + c) * 16 + l15] = (s / 16129.f) * LOG2E;
}

// dw f32 [b][t][256] -> per-lane floatx4 dwp[(bg*512+t)][tid]
__global__ __launch_bounds__(512) void repack_dw6(const float* __restrict__ dw, floatx4* __restrict__ dwp){
  int blk = blockIdx.x;                // bg*512 + t
  int t_ = blk & 511; int bg = blk >> 9;
  int tid = threadIdx.x;
  int w = tid >> 6, l = tid & 63;
  int l15 = l & 15, l4 = l >> 4;
  int jbL = l4 >> 1, rowH = (l4 & 1) * 4;
  int j = (jbL * 8 + w) * 16 + l15;
  floatx4 o;
  #pragma unroll
  for (int r = 0; r < 4; r++){
    int b = bg * 8 + rowH + r;
    o[r] = dw[((size_t)b * 512 + t_) * 256 + j];
  }
  dwp[(size_t)blk * 512 + tid] = o;
}

// hcp u64[(dirbg*512+ts)][tid] (4 f16 slots) -> hcat bf16 [b*512+ts][dir*256+j]
__global__ __launch_bounds__(256) void hcat_un6(const u16* __restrict__ hcp, u16* __restrict__ hcat){
  int row = blockIdx.x;                // b*512 + ts
  int b = row >> 9, ts = row & 511;
  int bg = b >> 3, br = b & 7;
  int rv = br & 3;
  int jj = threadIdx.x;
  int jb = jj >> 7, wv = (jj >> 4) & 7, c15 = jj & 15;
  int tidv = wv * 64 + (((jb << 1) | (br >> 2)) * 16) + c15;
  #pragma unroll
  for (int dir = 0; dir < 2; dir++){
    u16 hb = hcp[((((size_t)(dir * 4 + bg) * 512 + ts) * 512 + tidv) << 2) + rv];
    hcat[(size_t)row * 512 + dir * 256 + jj] = f2bf(h_bits2f(hb));
  }
}

// Vt[bh][d][kt] from qkv[b][kt][1024 + h*128 + d]
__global__ __launch_bounds__(256) void transpose_v_k(const u16* __restrict__ qkv, u16* __restrict__ Vt){
  __shared__ u16 tile[32][33];
  int bh = blockIdx.x, bb = bh >> 2, h = bh & 3;
  int kt0 = blockIdx.y << 5, d0 = blockIdx.z << 5;
  int tx = threadIdx.x, ty = threadIdx.y;
  for (int i = ty; i < 32; i += 8)
    tile[i][tx] = qkv[(size_t)(bb * 512 + kt0 + i) * 1536 + 1024 + h * 128 + d0 + tx];
  __syncthreads();
  for (int i = ty; i < 32; i += 8)
    Vt[((size_t)bh * 128 + d0 + i) * 512 + kt0 + tx] = tile[tx][i];
}

// ---------------- GEMM (A[M,K] row-major bf16, Bt[N,K] row-major bf16) ----------------
// OM: 0=f32, 1=bf16, 2=f16, 3=f16 in lstm per-lane packed layout (xgp; scalar stores —
// the 4 r-values are CONSECUTIVE TIME STEPS (m&511), not slots; they cannot be packed)

template<int OM>
__global__ __launch_bounds__(256) void gemm_bt(const u16* __restrict__ A, const u16* __restrict__ Bt,
                                               void* __restrict__ C, const float* __restrict__ bias,
                                               int M, int N, int K, int lda, int ldb, int ldc,
                                               long long aB1, long long aB2, long long bB1, long long bB2,
                                               long long cB1, long long cB2, int nb2, float scale){
  int tilesN = N >> 7;
  int bz = blockIdx.y;
  int b1 = bz / nb2, b2 = bz - b1 * nb2;
  const u16* Ab = A + (size_t)(b1 * aB1 + b2 * aB2);
  const u16* Bb = Bt + (size_t)(b1 * bB1 + b2 * bB2);
  size_t cOff = (size_t)(b1 * cB1 + b2 * cB2);
  int tm = blockIdx.x / tilesN, tn = blockIdx.x - tm * tilesN;
  int m0 = tm << 7, n0 = tn << 7;
  __shared__ u16 As[128 * 64];
  __shared__ u16 Bs[128 * 64];
  int t = threadIdx.x;
  int wave = t >> 6, lane = t & 63;
  int wr = wave >> 1, wc = wave & 1;
  int l15 = lane & 15, l4 = lane >> 4;
  floatx4 acc[4][4] = {};
  for (int k0 = 0; k0 < K; k0 += 64){
    #pragma unroll
    for (int i = 0; i < 4; i++){
      int chunk = t + (i << 8);
      int r = chunk >> 3, cx = chunk & 7;
      int sc = ((cx ^ (r & 7)) << 3);
      *(uint4*)(&As[(r << 6) + sc]) = *(const uint4*)(&Ab[(size_t)(m0 + r) * lda + k0 + (cx << 3)]);
      *(uint4*)(&Bs[(r << 6) + sc]) = *(const uint4*)(&Bb[(size_t)(n0 + r) * ldb + k0 + (cx << 3)]);
    }
    __syncthreads();
    #pragma unroll
    for (int kk = 0; kk < 2; kk++){
      bf16x8 af[4], bf[4];
      int co = (kk << 2) + l4;
      #pragma unroll
      for (int mi = 0; mi < 4; mi++){
        int r = (wr << 6) + (mi << 4) + l15;
        af[mi] = __builtin_bit_cast(bf16x8, *(const uint4*)(&As[(r << 6) + ((co ^ (r & 7)) << 3)]));
      }
      #pragma unroll
      for (int ni = 0; ni < 4; ni++){
        int r = (wc << 6) + (ni << 4) + l15;
        bf[ni] = __builtin_bit_cast(bf16x8, *(const uint4*)(&Bs[(r << 6) + ((co ^ (r & 7)) << 3)]));
      }
      #pragma unroll
      for (int mi = 0; mi < 4; mi++)
        #pragma unroll
        for (int ni = 0; ni < 4; ni++)
          acc[mi][ni] = __builtin_amdgcn_mfma_f32_16x16x32_bf16(af[mi], bf[ni], acc[mi][ni], 0, 0, 0);
    }
    __syncthreads();
  }
  #pragma unroll
  for (int mi = 0; mi < 4; mi++){
    int rowb = m0 + (wr << 6) + (mi << 4) + (l4 << 2);
    #pragma unroll
    for (int ni = 0; ni < 4; ni++){
      int col = n0 + (wc << 6) + (ni << 4) + l15;
      float bv = bias ? bias[col] : 0.f;
      #pragma unroll
      for (int r = 0; r < 4; r++){
        float val = acc[mi][ni][r] * scale + bv;
        if (OM == 3){
          int m = rowb + r, n = col;
          int bb2 = m >> 9, tt2 = m & 511;
          int dirX = (n >= 1280) ? 1 : 0;
          int rem = n - dirX * 1280;
          int g2 = rem >> 8, j2 = rem & 255;
          int bg2 = bb2 >> 3, br2 = bb2 & 7;
          int tid2 = ((j2 >> 4) & 7) * 64 + ((((j2 >> 7) << 1) | (br2 >> 2)) << 4) + (j2 & 15);
          size_t idx = ((((size_t)(dirX * 4 + bg2) * 512 + tt2) * 5 + g2) * 512 + tid2) * 4 + (br2 & 3);
          ((u16*)C)[idx] = f2h_bits(val);
        } else {
          size_t off = cOff + (size_t)(rowb + r) * ldc + col;
          if (OM == 0) ((float*)C)[off] = val;
          else if (OM == 1) ((u16*)C)[off] = f2bf(val);
          else ((u16*)C)[off] = f2h_bits(val);
        }
      }
    }
  }
}

// ---------------- LSTM recurrence: 8 WGs (dir x 4 batch-groups of 8), i8 MFMA ----------------
// rec13 = rec11 (proven) + batched shfl redistribution (all 20 ds_bpermute issued before the
// selects -> single lgkm drain). Gate math and OM=3 scatter are byte-identical to passing R11;
// R12's u64-pack (wrong: r varies TIME not slot) and merged-rcp (P3 f32-overflow -> NaN) reverted.

#define LSTM_STEP(S, XQC, DVC, XQN, DVN, HRD, HWR)                                         \
{                                                                                          \
  int ts = dir ? (511 - (S)) : (S);                                                        \
  int spc = ((S) + 1) & 511;                                                               \
  int tsn = dir ? (511 - spc) : spc;                                                       \
  _Pragma("unroll")                                                                        \
  for (int g = 0; g < 5; g++)                                                              \
    XQN[g] = xgp[(((size_t)dirbg * 512 + tsn) * 5 + g) * 512 + t];                         \
  DVN = dwp[((size_t)bg * 512 + tsn) * 512 + t];                                           \
  int32x4 a[4];                                                                            \
  _Pragma("unroll")                                                                        \
  for (int ks = 0; ks < 4; ks++){                                                          \
    int kblk = ks * 4 + l4;                                                                \
    a[ks] = *(const int32x4*)&(HRD)[l15 * 256 + ((kblk ^ l15) & 15) * 16];                 \
  }                                                                                        \
  int32x4 accA[5] = {}, accB[5] = {};                                                      \
  _Pragma("unroll")                                                                        \
  for (int g = 0; g < 5; g++)                                                              \
    _Pragma("unroll")                                                                      \
    for (int ks = 0; ks < 4; ks++)                                                         \
      accA[g] = __builtin_amdgcn_mfma_i32_16x16x64_i8(a[ks], uf[g][ks], accA[g], 0, 0, 0); \
  _Pragma("unroll")                                                                        \
  for (int g = 0; g < 5; g++)                                                              \
    _Pragma("unroll")                                                                      \
    for (int ks = 0; ks < 4; ks++)                                                         \
      accB[g] = __builtin_amdgcn_mfma_i32_16x16x64_i8(a[ks], uf[5 + g][ks], accB[g], 0, 0, 0); \
  int vbx[5][4];                                                                           \
  _Pragma("unroll")                                                                        \
  for (int g = 0; g < 5; g++)                                                              \
    _Pragma("unroll")                                                                      \
    for (int r = 0; r < 4; r++)                                                            \
      vbx[g][r] = __shfl(accB[g][r], l ^ 32, 64);                                          \
  _Pragma("unroll")                                                                        \
  for (int g = 0; g < 5; g++)                                                              \
    _Pragma("unroll")                                                                      \
    for (int r = 0; r < 4; r++)                                                            \
      accA[g][r] = hiHalf ? vbx[g][r] : accA[g][r];                                        \
  u32 hp0 = 0, hp1 = 0;                                                                    \
  _Pragma("unroll")                                                                        \
  for (int r = 0; r < 4; r++){                                                             \
    float y[5];                                                                            \
    _Pragma("unroll")                                                                      \
    for (int g = 0; g < 5; g++)                                                            \
      y[g] = (float)accA[g][r] * csv5[g] + h_bits2f((u16)(XQC[g] >> (16 * r)));            \
    float ei = exp2n(y[0]), ef = exp2n(y[1]), eo = exp2n(y[2]);                            \
    float ec = exp2n(fmaxf(y[3] + y[3], -100.f));                                          \
    float es = exp2n(y[4]);                                                                \
    float P3 = (1.f + ei) * (1.f + ec) * (1.f + es);                                       \
    float term = (1.f - ec) * DVC[r] * rcp_(P3);                                           \
    cst[r] = cst[r] * rcp_(1.f + ef) + term;                                               \
    float ecc = exp2n(fmaxf(cst[r] * (2.f * LOG2E), -100.f));                              \
    float hv = (1.f - ecc) * rcp_((1.f + eo) * (1.f + ecc));                               \
    u16 h16 = f2h_bits(hv);                                                                \
    if (r < 2){ hp0 |= (u32)h16 << (16 * r); } else { hp1 |= (u32)h16 << (16 * (r - 2)); } \
    int row = rowH + r;                                                                    \
    (HWR)[row * 256 + (((jlane >> 4) ^ row) & 15) * 16 + (jlane & 15)] =                   \
        (signed char)(int)rintf(hv * 127.f);                                               \
  }                                                                                        \
  hcp[((size_t)dirbg * 512 + ts) * 512 + t] = (u64)hp0 | ((u64)hp1 << 32);                 \
  bar_lds();                                                                               \
}

__global__ __launch_bounds__(512, 2) void lstm_rec13(const u64* __restrict__ xgp, const floatx4* __restrict__ dwp,
                                                     const signed char* __restrict__ ufr, const float* __restrict__ cs,
                                                     u64* __restrict__ hcp){
  int dirbg = blockIdx.x;              // dir*4 + bg
  int dir = dirbg >> 2, bg = dirbg & 3;
  int t = threadIdx.x;
  int w = t >> 6, l = t & 63;
  int l15 = l & 15, l4 = l >> 4;
  int jbL = l4 >> 1;
  int rowH = (l4 & 1) * 4;
  int hiHalf = l & 32;
  __shared__ __align__(16) signed char hB[2][4096];   // h i8 dbuf [16 row][16 kblk^row][16]
  ((uint4*)hB)[t] = uint4{0, 0, 0, 0};                // zero both buffers
  const int32x4* ug = (const int32x4*)ufr;
  size_t ubase = ((size_t)(dir * 8 + w) * 10) * 4 * 64;
  int32x4 uf[10][4];                                  // ALL of wave's U slice (unified VGPR/AGPR file)
  #pragma unroll
  for (int c = 0; c < 10; c++)
    #pragma unroll
    for (int ks = 0; ks < 4; ks++)
      uf[c][ks] = ug[ubase + ((size_t)c * 4 + ks) * 64 + l];
  float csv5[5];
  #pragma unroll
  for (int g = 0; g < 5; g++)
    csv5[g] = cs[((size_t)(dir * 8 + w) * 10 + jbL * 5 + g) * 16 + l15];
  int jlane = (jbL * 8 + w) * 16 + l15;
  float cst[4] = {0.f, 0.f, 0.f, 0.f};
  // preload step 0 into buffer A
  u64 xqA[5], xqB[5];
  floatx4 dvA, dvB;
  {
    int ts0 = dir ? 511 : 0;
    #pragma unroll
    for (int g = 0; g < 5; g++)
      xqA[g] = xgp[(((size_t)dirbg * 512 + ts0) * 5 + g) * 512 + t];
    dvA = dwp[((size_t)bg * 512 + ts0) * 512 + t];
  }
  __syncthreads();
  for (int s2 = 0; s2 < 512; s2 += 2){
    LSTM_STEP(s2,     xqA, dvA, xqB, dvB, hB[1], hB[0]);   // even step: read hB[1], write hB[0]
    LSTM_STEP(s2 + 1, xqB, dvB, xqA, dvA, hB[0], hB[1]);   // odd step:  read hB[0], write hB[1]
  }
}

// ---------------- softmax (in-place bf16 rows of 512) ----------------

__global__ __launch_bounds__(256) void softmax_rows(u16* __restrict__ S){
  int row = blockIdx.x * 4 + (threadIdx.x >> 6);
  int l = threadIdx.x & 63;
  u16* r = S + (size_t)row * 512;
  uint4 v = *(const uint4*)(r + l * 8);
  u32 wsv[4] = {v.x, v.y, v.z, v.w};
  float f[8];
  #pragma unroll
  for (int i = 0; i < 4; i++){
    f[2 * i] = bf2f((u16)(wsv[i] & 0xFFFF));
    f[2 * i + 1] = bf2f((u16)(wsv[i] >> 16));
  }
  float mx = f[0];
  #pragma unroll
  for (int i = 1; i < 8; i++) mx = fmaxf(mx, f[i]);
  for (int m = 1; m < 64; m <<= 1) mx = fmaxf(mx, __shfl_xor(mx, m, 64));
  float e[8], s = 0.f;
  #pragma unroll
  for (int i = 0; i < 8; i++){ e[i] = __expf(f[i] - mx); s += e[i]; }
  for (int m = 1; m < 64; m <<= 1) s += __shfl_xor(s, m, 64);
  float inv = 1.f / s;
  uint4 o;
  u32 ov[4];
  #pragma unroll
  for (int i = 0; i < 4; i++)
    ov[i] = (u32)f2bf(e[2 * i] * inv) | ((u32)f2bf(e[2 * i + 1] * inv) << 16);
  o.x = ov[0]; o.y = ov[1]; o.z = ov[2]; o.w = ov[3];
  *(uint4*)(r + l * 8) = o;
}

// ---------------- layernorm (rows of 512, f32) ----------------

__global__ __launch_bounds__(256) void ln_rows(const float* __restrict__ X, const float* __restrict__ g,
                                               const float* __restrict__ be, float* __restrict__ out){
  int row = blockIdx.x * 4 + (threadIdx.x >> 6);
  int l = threadIdx.x & 63;
  const floatx4* p = (const floatx4*)(X + (size_t)row * 512);
  floatx4 aa = p[l * 2], bb = p[l * 2 + 1];
  float v[8];
  #pragma unroll
  for (int i = 0; i < 4; i++){ v[i] = aa[i]; v[4 + i] = bb[i]; }
  float s = 0.f, s2 = 0.f;
  #pragma unroll
  for (int i = 0; i < 8; i++){ s += v[i]; s2 += v[i] * v[i]; }
  for (int m = 1; m < 64; m <<= 1){ s += __shfl_xor(s, m, 64); s2 += __shfl_xor(s2, m, 64); }
  float mu = s * (1.f / 512.f);
  float var = s2 * (1.f / 512.f) - mu * mu;
  float rs = rsqrtf(var + 1e-5f);
  int c0 = l * 8;
  float* orow = out + (size_t)row * 512;
  #pragma unroll
  for (int i = 0; i < 8; i++)
    orow[c0 + i] = (v[i] - mu) * rs * g[c0 + i] + be[c0 + i];
}

// ---------------- launch ----------------

extern "C" void kernel_launch(void* const* d_in, const int* in_sizes, int n_in,
                              void* d_out, int out_size, void* d_ws, size_t ws_size,
                              hipStream_t stream){
  (void)in_sizes; (void)n_in; (void)out_size; (void)ws_size;
  const float* x    = (const float*)d_in[0];
  const float* gw   = (const float*)d_in[1];
  const float* Wf   = (const float*)d_in[2];
  const float* bWf  = (const float*)d_in[3];
  const float* Uf   = (const float*)d_in[4];
  const float* bUf  = (const float*)d_in[5];
  const float* Wb   = (const float*)d_in[6];
  const float* bWb  = (const float*)d_in[7];
  const float* Ub   = (const float*)d_in[8];
  const float* bUb  = (const float*)d_in[9];
  const float* inw  = (const float*)d_in[10];
  const float* inb  = (const float*)d_in[11];
  const float* outw = (const float*)d_in[12];
  const float* outb = (const float*)d_in[13];
  const float* gam  = (const float*)d_in[14];
  const float* bet  = (const float*)d_in[15];
  char* ws = (char*)d_ws;

  size_t o = 0;
  auto take = [&](size_t bytes){ size_t r = o; o += (bytes + 255) & ~(size_t)255; return r; };
  size_t o_xb   = take(16384ULL * 256 * 2);
  size_t o_wt   = take(2560ULL * 256 * 2);
  size_t o_bias = take(2560ULL * 4);
  size_t o_inw  = take(1536ULL * 512 * 2);
  size_t o_outw = take(512ULL * 512 * 2);
  size_t o_ufr  = take(655360);                 // i8 U frags
  size_t o_cs   = take(2ULL * 8 * 10 * 16 * 4); // col scales
  size_t o_dwp  = take(4ULL * 512 * 512 * 16);  // repacked dw (per-lane floatx4)
  size_t o_hcp  = take(8ULL * 512 * 512 * 8);   // packed f16 h (u64/lane)
  size_t o_hcat = take(16384ULL * 512 * 2);
  size_t o_xg   = take(16384ULL * 2560 * 2);    // xgp (exact fit); later qkv (base) + attno (+48MB)
  size_t o_vt   = take(128ULL * 128 * 512 * 2);
  size_t o_S    = take(128ULL * 512 * 512 * 2); // scores; later preln (f32)
  size_t o_qkv  = o_xg;
  size_t o_attn = o_xg + 16384ULL * 1536 * 2;
  size_t o_xgp  = o_xg;                         // 8*512*5*512*8 = 83886080 == o_xg size
  size_t o_pre  = o_S;

  u16* xb     = (u16*)(ws + o_xb);
  u16* Wt     = (u16*)(ws + o_wt);
  float* bWU  = (float*)(ws + o_bias);
  u16* inwb   = (u16*)(ws + o_inw);
  u16* outwb  = (u16*)(ws + o_outw);
  signed char* ufr = (signed char*)(ws + o_ufr);
  float* cs   = (float*)(ws + o_cs);
  floatx4* dwp = (floatx4*)(ws + o_dwp);
  u64* hcp    = (u64*)(ws + o_hcp);
  u16* hcat   = (u16*)(ws + o_hcat);
  u64* xgp    = (u64*)(ws + o_xgp);
  u16* qkv    = (u16*)(ws + o_qkv);
  u16* attn   = (u16*)(ws + o_attn);
  u16* Vt     = (u16*)(ws + o_vt);
  u16* S      = (u16*)(ws + o_S);
  float* pre  = (float*)(ws + o_pre);

  conv_bf16_k<<<4096, 256, 0, stream>>>(x, xb, 16384 * 256);
  conv_bf16_k<<<1024, 256, 0, stream>>>(inw, inwb, 1536 * 512);
  conv_bf16_k<<<512, 256, 0, stream>>>(outw, outwb, 512 * 512);
  prep_wt_k<<<2560, 256, 0, stream>>>(Wf, Wb, bWf, bWb, bUf, bUb, Wt, bWU);
  prep_uq<<<2560, 256, 0, stream>>>(Uf, Ub, ufr, cs);
  repack_dw6<<<2048, 512, 0, stream>>>(gw, dwp);

  // xg = (x @ Wt^T)*log2e + (bW+bU)*log2e, written DIRECTLY in per-lane packed layout
  gemm_bt<3><<<dim3(2560, 1), 256, 0, stream>>>(xb, Wt, (void*)xgp, bWU,
      16384, 2560, 256, 256, 256, 2560, 0, 0, 0, 0, 0, 0, 1, LOG2E);

  lstm_rec13<<<8, 512, 0, stream>>>(xgp, dwp, ufr, cs, hcp);

  hcat_un6<<<16384, 256, 0, stream>>>((const u16*)hcp, hcat);

  // qkv = hcat @ in_proj_w^T + b, bf16, [16384][1536]  (overwrites xgp region)
  gemm_bt<1><<<dim3(1536, 1), 256, 0, stream>>>(hcat, inwb, (void*)qkv, inb,
      16384, 1536, 512, 512, 512, 1536, 0, 0, 0, 0, 0, 0, 1, 1.f);

  transpose_v_k<<<dim3(128, 16, 4), dim3(32, 8), 0, stream>>>(qkv, Vt);

  // scores: per (b,h): Q[512,128] @ K^T -> S bf16 [bh][512][512], scaled
  gemm_bt<1><<<dim3(16, 128), 256, 0, stream>>>(qkv, qkv + 512, (void*)S, nullptr,
      512, 512, 128, 1536, 1536, 512,
      786432LL, 128LL, 786432LL, 128LL, 1048576LL, 262144LL, 4, 0.08838834764831845f);

  softmax_rows<<<16384, 256, 0, stream>>>(S);

  // PV: P[512,512] @ Vt^T -> attno[b][t][h*128+d] bf16
  gemm_bt<1><<<dim3(4, 128), 256, 0, stream>>>(S, Vt, (void*)attn, nullptr,
      512, 128, 512, 512, 512, 512,
      1048576LL, 262144LL, 262144LL, 65536LL, 262144LL, 128LL, 4, 1.f);

  // out proj: attno @ out_w^T + b -> preln f32
  gemm_bt<0><<<dim3(512, 1), 256, 0, stream>>>(attn, outwb, (void*)pre, outb,
      16384, 512, 512, 512, 512, 512, 0, 0, 0, 0, 0, 0, 1, 1.f);

  ln_rows<<<4096, 256, 0, stream>>>(pre, gam, bet, (float*)d_out);
}

// Round 14
// 981.584 us; speedup vs baseline: 1.0415x; 1.0415x over previous
//
#include <hip/hip_runtime.h>

typedef unsigned int u32;
typedef unsigned short u16;
typedef unsigned long long u64;
typedef float floatx4 __attribute__((ext_vector_type(4)));
typedef int int32x4 __attribute__((ext_vector_type(4)));
typedef __bf16 bf16x8 __attribute__((ext_vector_type(8)));

#define DEV __device__ __forceinline__
#define LOG2E 1.4426950408889634f

DEV u16 f2bf(float f){
  u32 u = __builtin_bit_cast(u32, f);
  u += 0x7FFFu + ((u >> 16) & 1u);
  return (u16)(u >> 16);
}
DEV float bf2f(u16 h){ u32 u = ((u32)h) << 16; return __builtin_bit_cast(float, u); }
DEV u16 f2h_bits(float f){ return __builtin_bit_cast(u16, (_Float16)f); }
DEV float h_bits2f(u16 h){ return (float)__builtin_bit_cast(_Float16, h); }
// fast transcendentals, guaranteed single-instruction
DEV float exp2n(float x){ float r; asm("v_exp_f32 %0, -%1" : "=v"(r) : "v"(x)); return r; }      // 2^-x
DEV float rcp_(float x){ float r; asm("v_rcp_f32 %0, %1" : "=v"(r) : "v"(x)); return r; }
// LDS-only barrier: orders ds ops across waves WITHOUT draining vmcnt (prefetch loads stay in flight).
DEV void bar_lds(){
  __builtin_amdgcn_sched_barrier(0);
  asm volatile("s_waitcnt lgkmcnt(0)" ::: "memory");
  __builtin_amdgcn_s_barrier();
  __builtin_amdgcn_sched_barrier(0);
}

// ---------------- prep kernels ----------------

__global__ __launch_bounds__(256) void conv_bf16_k(const float* __restrict__ src, u16* __restrict__ dst, int n){
  for (int i = blockIdx.x * 256 + threadIdx.x; i < n; i += gridDim.x * 256)
    dst[i] = f2bf(src[i]);
}

// Wt[n][k] (n = dir*1280 + g*256 + h, k = i), bf16; biasWU[n] = (bW+bU)*log2e (log2-domain gates)
__global__ __launch_bounds__(256) void prep_wt_k(const float* __restrict__ Wf, const float* __restrict__ Wb,
                                                 const float* __restrict__ bWf, const float* __restrict__ bWb,
                                                 const float* __restrict__ bUf, const float* __restrict__ bUb,
                                                 u16* __restrict__ Wt, float* __restrict__ biasWU){
  int idx = blockIdx.x * 256 + threadIdx.x;
  if (idx >= 2560 * 256) return;
  int n = idx >> 8, k = idx & 255;
  int dir = n / 1280, rr = n - dir * 1280, g = rr >> 8, hc = rr & 255;
  const float* W = dir ? Wb : Wf;
  Wt[idx] = f2bf(W[(g * 256 + k) * 256 + hc]);
  if (k == 0)
    biasWU[n] = ((dir ? bWb : bWf)[g * 256 + hc] + (dir ? bUb : bUf)[g * 256 + hc]) * LOG2E;
}

// U -> i8 MFMA B-fragments + per-column scales (scaled by log2e).
__global__ __launch_bounds__(256) void prep_uq(const float* __restrict__ Uf, const float* __restrict__ Ub,
                                               signed char* __restrict__ ufr, float* __restrict__ cs){
  int colid = blockIdx.x;              // dir*1280 + g*256 + j
  int dir = colid / 1280; int rr = colid - dir * 1280; int g = rr >> 8; int j = rr & 255;
  int k = threadIdx.x;
  const float* U = dir ? Ub : Uf;
  float v = U[((size_t)g * 256 + k) * 256 + j];
  __shared__ float red[256];
  red[k] = fabsf(v); __syncthreads();
  for (int s = 128; s > 0; s >>= 1){ if (k < s) red[k] = fmaxf(red[k], red[k + s]); __syncthreads(); }
  float s = red[0];
  float q = (s > 0.f) ? 127.f / s : 0.f;
  int iq = (int)rintf(v * q);
  int jb = j >> 4, l15 = j & 15;
  int w = jb & 7, jbsel = jb >> 3;
  int c = jbsel * 5 + g;
  int ks = k >> 6, lsub = (k >> 4) & 3, e = k & 15;
  int lane = lsub * 16 + l15;
  ufr[((((size_t)(dir * 8 + w) * 10 + c) * 4 + ks) * 64 + lane) * 16 + e] = (signed char)iq;
  if (k == 0) cs[((size_t)(dir * 8 + w) * 10 + c) * 16 + l15] = (s / 16129.f) * LOG2E;
}

// dw f32 [b][t][256] -> per-lane floatx4 dwp[(bg*512+t)][tid]
__global__ __launch_bounds__(512) void repack_dw6(const float* __restrict__ dw, floatx4* __restrict__ dwp){
  int blk = blockIdx.x;                // bg*512 + t
  int t_ = blk & 511; int bg = blk >> 9;
  int tid = threadIdx.x;
  int w = tid >> 6, l = tid & 63;
  int l15 = l & 15, l4 = l >> 4;
  int jbL = l4 >> 1, rowH = (l4 & 1) * 4;
  int j = (jbL * 8 + w) * 16 + l15;
  floatx4 o;
  #pragma unroll
  for (int r = 0; r < 4; r++){
    int b = bg * 8 + rowH + r;
    o[r] = dw[((size_t)b * 512 + t_) * 256 + j];
  }
  dwp[(size_t)blk * 512 + tid] = o;
}

// hcp u64[(dirbg*512+ts)][tid] (4 f16 slots) -> hcat bf16 [b*512+ts][dir*256+j]
__global__ __launch_bounds__(256) void hcat_un6(const u16* __restrict__ hcp, u16* __restrict__ hcat){
  int row = blockIdx.x;                // b*512 + ts
  int b = row >> 9, ts = row & 511;
  int bg = b >> 3, br = b & 7;
  int rv = br & 3;
  int jj = threadIdx.x;
  int jb = jj >> 7, wv = (jj >> 4) & 7, c15 = jj & 15;
  int tidv = wv * 64 + (((jb << 1) | (br >> 2)) * 16) + c15;
  #pragma unroll
  for (int dir = 0; dir < 2; dir++){
    u16 hb = hcp[((((size_t)(dir * 4 + bg) * 512 + ts) * 512 + tidv) << 2) + rv];
    hcat[(size_t)row * 512 + dir * 256 + jj] = f2bf(h_bits2f(hb));
  }
}

// Vt[bh][d][kt] from qkv[b][kt][1024 + h*128 + d]
__global__ __launch_bounds__(256) void transpose_v_k(const u16* __restrict__ qkv, u16* __restrict__ Vt){
  __shared__ u16 tile[32][33];
  int bh = blockIdx.x, bb = bh >> 2, h = bh & 3;
  int kt0 = blockIdx.y << 5, d0 = blockIdx.z << 5;
  int tx = threadIdx.x, ty = threadIdx.y;
  for (int i = ty; i < 32; i += 8)
    tile[i][tx] = qkv[(size_t)(bb * 512 + kt0 + i) * 1536 + 1024 + h * 128 + d0 + tx];
  __syncthreads();
  for (int i = ty; i < 32; i += 8)
    Vt[((size_t)bh * 128 + d0 + i) * 512 + kt0 + tx] = tile[tx][i];
}

// ---------------- GEMM (A[M,K] row-major bf16, Bt[N,K] row-major bf16) ----------------
// OM: 0=f32, 1=bf16, 2=f16, 3=f16 in lstm per-lane packed layout (xgp)

template<int OM>
__global__ __launch_bounds__(256) void gemm_bt(const u16* __restrict__ A, const u16* __restrict__ Bt,
                                               void* __restrict__ C, const float* __restrict__ bias,
                                               int M, int N, int K, int lda, int ldb, int ldc,
                                               long long aB1, long long aB2, long long bB1, long long bB2,
                                               long long cB1, long long cB2, int nb2, float scale){
  int tilesN = N >> 7;
  int bz = blockIdx.y;
  int b1 = bz / nb2, b2 = bz - b1 * nb2;
  const u16* Ab = A + (size_t)(b1 * aB1 + b2 * aB2);
  const u16* Bb = Bt + (size_t)(b1 * bB1 + b2 * bB2);
  size_t cOff = (size_t)(b1 * cB1 + b2 * cB2);
  int tm = blockIdx.x / tilesN, tn = blockIdx.x - tm * tilesN;
  int m0 = tm << 7, n0 = tn << 7;
  __shared__ u16 As[128 * 64];
  __shared__ u16 Bs[128 * 64];
  int t = threadIdx.x;
  int wave = t >> 6, lane = t & 63;
  int wr = wave >> 1, wc = wave & 1;
  int l15 = lane & 15, l4 = lane >> 4;
  floatx4 acc[4][4] = {};
  for (int k0 = 0; k0 < K; k0 += 64){
    #pragma unroll
    for (int i = 0; i < 4; i++){
      int chunk = t + (i << 8);
      int r = chunk >> 3, cx = chunk & 7;
      int sc = ((cx ^ (r & 7)) << 3);
      *(uint4*)(&As[(r << 6) + sc]) = *(const uint4*)(&Ab[(size_t)(m0 + r) * lda + k0 + (cx << 3)]);
      *(uint4*)(&Bs[(r << 6) + sc]) = *(const uint4*)(&Bb[(size_t)(n0 + r) * ldb + k0 + (cx << 3)]);
    }
    __syncthreads();
    #pragma unroll
    for (int kk = 0; kk < 2; kk++){
      bf16x8 af[4], bf[4];
      int co = (kk << 2) + l4;
      #pragma unroll
      for (int mi = 0; mi < 4; mi++){
        int r = (wr << 6) + (mi << 4) + l15;
        af[mi] = __builtin_bit_cast(bf16x8, *(const uint4*)(&As[(r << 6) + ((co ^ (r & 7)) << 3)]));
      }
      #pragma unroll
      for (int ni = 0; ni < 4; ni++){
        int r = (wc << 6) + (ni << 4) + l15;
        bf[ni] = __builtin_bit_cast(bf16x8, *(const uint4*)(&Bs[(r << 6) + ((co ^ (r & 7)) << 3)]));
      }
      #pragma unroll
      for (int mi = 0; mi < 4; mi++)
        #pragma unroll
        for (int ni = 0; ni < 4; ni++)
          acc[mi][ni] = __builtin_amdgcn_mfma_f32_16x16x32_bf16(af[mi], bf[ni], acc[mi][ni], 0, 0, 0);
    }
    __syncthreads();
  }
  #pragma unroll
  for (int mi = 0; mi < 4; mi++){
    int rowb = m0 + (wr << 6) + (mi << 4) + (l4 << 2);
    #pragma unroll
    for (int ni = 0; ni < 4; ni++){
      int col = n0 + (wc << 6) + (ni << 4) + l15;
      float bv = bias ? bias[col] : 0.f;
      #pragma unroll
      for (int r = 0; r < 4; r++){
        float val = acc[mi][ni][r] * scale + bv;
        if (OM == 3){
          int m = rowb + r, n = col;
          int bb2 = m >> 9, tt2 = m & 511;
          int dirX = (n >= 1280) ? 1 : 0;
          int rem = n - dirX * 1280;
          int g2 = rem >> 8, j2 = rem & 255;
          int bg2 = bb2 >> 3, br2 = bb2 & 7;
          int tid2 = ((j2 >> 4) & 7) * 64 + ((((j2 >> 7) << 1) | (br2 >> 2)) << 4) + (j2 & 15);
          size_t idx = ((((size_t)(dirX * 4 + bg2) * 512 + tt2) * 5 + g2) * 512 + tid2) * 4 + (br2 & 3);
          ((u16*)C)[idx] = f2h_bits(val);
        } else {
          size_t off = cOff + (size_t)(rowb + r) * ldc + col;
          if (OM == 0) ((float*)C)[off] = val;
          else if (OM == 1) ((u16*)C)[off] = f2bf(val);
          else ((u16*)C)[off] = f2h_bits(val);
        }
      }
    }
  }
}

// ---------------- LSTM recurrence: 8 WGs (dir x 4 batch-groups of 8), i8 MFMA ----------------
// rec14 == rec11 verbatim (best measured: 730us, absmax 0.0117). R13's batched-shfl variant
// regressed (+42us: vbx staging array extended 20 live ranges at ~200 regs live); interleaved
// shfl+select is the proven optimum. U fully register-resident, LDS = 8KB hB only.

#define LSTM_STEP(S, XQC, DVC, XQN, DVN, HRD, HWR)                                         \
{                                                                                          \
  int ts = dir ? (511 - (S)) : (S);                                                        \
  int spc = ((S) + 1) & 511;                                                               \
  int tsn = dir ? (511 - spc) : spc;                                                       \
  _Pragma("unroll")                                                                        \
  for (int g = 0; g < 5; g++)                                                              \
    XQN[g] = xgp[(((size_t)dirbg * 512 + tsn) * 5 + g) * 512 + t];                         \
  DVN = dwp[((size_t)bg * 512 + tsn) * 512 + t];                                           \
  int32x4 a[4];                                                                            \
  _Pragma("unroll")                                                                        \
  for (int ks = 0; ks < 4; ks++){                                                          \
    int kblk = ks * 4 + l4;                                                                \
    a[ks] = *(const int32x4*)&(HRD)[l15 * 256 + ((kblk ^ l15) & 15) * 16];                 \
  }                                                                                        \
  int32x4 accA[5] = {}, accB[5] = {};                                                      \
  _Pragma("unroll")                                                                        \
  for (int g = 0; g < 5; g++)                                                              \
    _Pragma("unroll")                                                                      \
    for (int ks = 0; ks < 4; ks++)                                                         \
      accA[g] = __builtin_amdgcn_mfma_i32_16x16x64_i8(a[ks], uf[g][ks], accA[g], 0, 0, 0); \
  _Pragma("unroll")                                                                        \
  for (int g = 0; g < 5; g++)                                                              \
    _Pragma("unroll")                                                                      \
    for (int ks = 0; ks < 4; ks++)                                                         \
      accB[g] = __builtin_amdgcn_mfma_i32_16x16x64_i8(a[ks], uf[5 + g][ks], accB[g], 0, 0, 0); \
  _Pragma("unroll")                                                                        \
  for (int g = 0; g < 5; g++)                                                              \
    _Pragma("unroll")                                                                      \
    for (int r = 0; r < 4; r++){                                                           \
      int vbx = __shfl(accB[g][r], l ^ 32, 64);                                            \
      accA[g][r] = hiHalf ? vbx : accA[g][r];                                              \
    }                                                                                      \
  u32 hp0 = 0, hp1 = 0;                                                                    \
  _Pragma("unroll")                                                                        \
  for (int r = 0; r < 4; r++){                                                             \
    float y[5];                                                                            \
    _Pragma("unroll")                                                                      \
    for (int g = 0; g < 5; g++)                                                            \
      y[g] = (float)accA[g][r] * csv5[g] + h_bits2f((u16)(XQC[g] >> (16 * r)));            \
    float ei = exp2n(y[0]), ef = exp2n(y[1]), eo = exp2n(y[2]);                            \
    float ec = exp2n(fmaxf(y[3] + y[3], -100.f));                                          \
    float es = exp2n(y[4]);                                                                \
    float P3 = (1.f + ei) * (1.f + ec) * (1.f + es);                                       \
    float term = (1.f - ec) * DVC[r] * rcp_(P3);                                           \
    cst[r] = cst[r] * rcp_(1.f + ef) + term;                                               \
    float ecc = exp2n(fmaxf(cst[r] * (2.f * LOG2E), -100.f));                              \
    float hv = (1.f - ecc) * rcp_((1.f + eo) * (1.f + ecc));                               \
    u16 h16 = f2h_bits(hv);                                                                \
    if (r < 2){ hp0 |= (u32)h16 << (16 * r); } else { hp1 |= (u32)h16 << (16 * (r - 2)); } \
    int row = rowH + r;                                                                    \
    (HWR)[row * 256 + (((jlane >> 4) ^ row) & 15) * 16 + (jlane & 15)] =                   \
        (signed char)(int)rintf(hv * 127.f);                                               \
  }                                                                                        \
  hcp[((size_t)dirbg * 512 + ts) * 512 + t] = (u64)hp0 | ((u64)hp1 << 32);                 \
  bar_lds();                                                                               \
}

__global__ __launch_bounds__(512, 2) void lstm_rec14(const u64* __restrict__ xgp, const floatx4* __restrict__ dwp,
                                                     const signed char* __restrict__ ufr, const float* __restrict__ cs,
                                                     u64* __restrict__ hcp){
  int dirbg = blockIdx.x;              // dir*4 + bg
  int dir = dirbg >> 2, bg = dirbg & 3;
  int t = threadIdx.x;
  int w = t >> 6, l = t & 63;
  int l15 = l & 15, l4 = l >> 4;
  int jbL = l4 >> 1;
  int rowH = (l4 & 1) * 4;
  int hiHalf = l & 32;
  __shared__ __align__(16) signed char hB[2][4096];   // h i8 dbuf [16 row][16 kblk^row][16]
  ((uint4*)hB)[t] = uint4{0, 0, 0, 0};                // zero both buffers
  const int32x4* ug = (const int32x4*)ufr;
  size_t ubase = ((size_t)(dir * 8 + w) * 10) * 4 * 64;
  int32x4 uf[10][4];                                  // ALL of wave's U slice (unified VGPR/AGPR file)
  #pragma unroll
  for (int c = 0; c < 10; c++)
    #pragma unroll
    for (int ks = 0; ks < 4; ks++)
      uf[c][ks] = ug[ubase + ((size_t)c * 4 + ks) * 64 + l];
  float csv5[5];
  #pragma unroll
  for (int g = 0; g < 5; g++)
    csv5[g] = cs[((size_t)(dir * 8 + w) * 10 + jbL * 5 + g) * 16 + l15];
  int jlane = (jbL * 8 + w) * 16 + l15;
  float cst[4] = {0.f, 0.f, 0.f, 0.f};
  // preload step 0 into buffer A
  u64 xqA[5], xqB[5];
  floatx4 dvA, dvB;
  {
    int ts0 = dir ? 511 : 0;
    #pragma unroll
    for (int g = 0; g < 5; g++)
      xqA[g] = xgp[(((size_t)dirbg * 512 + ts0) * 5 + g) * 512 + t];
    dvA = dwp[((size_t)bg * 512 + ts0) * 512 + t];
  }
  __syncthreads();
  for (int s2 = 0; s2 < 512; s2 += 2){
    LSTM_STEP(s2,     xqA, dvA, xqB, dvB, hB[1], hB[0]);   // even step: read hB[1], write hB[0]
    LSTM_STEP(s2 + 1, xqB, dvB, xqA, dvA, hB[0], hB[1]);   // odd step:  read hB[0], write hB[1]
  }
}

// ---------------- softmax (in-place bf16 rows of 512) ----------------

__global__ __launch_bounds__(256) void softmax_rows(u16* __restrict__ S){
  int row = blockIdx.x * 4 + (threadIdx.x >> 6);
  int l = threadIdx.x & 63;
  u16* r = S + (size_t)row * 512;
  uint4 v = *(const uint4*)(r + l * 8);
  u32 wsv[4] = {v.x, v.y, v.z, v.w};
  float f[8];
  #pragma unroll
  for (int i = 0; i < 4; i++){
    f[2 * i] = bf2f((u16)(wsv[i] & 0xFFFF));
    f[2 * i + 1] = bf2f((u16)(wsv[i] >> 16));
  }
  float mx = f[0];
  #pragma unroll
  for (int i = 1; i < 8; i++) mx = fmaxf(mx, f[i]);
  for (int m = 1; m < 64; m <<= 1) mx = fmaxf(mx, __shfl_xor(mx, m, 64));
  float e[8], s = 0.f;
  #pragma unroll
  for (int i = 0; i < 8; i++){ e[i] = __expf(f[i] - mx); s += e[i]; }
  for (int m = 1; m < 64; m <<= 1) s += __shfl_xor(s, m, 64);
  float inv = 1.f / s;
  uint4 o;
  u32 ov[4];
  #pragma unroll
  for (int i = 0; i < 4; i++)
    ov[i] = (u32)f2bf(e[2 * i] * inv) | ((u32)f2bf(e[2 * i + 1] * inv) << 16);
  o.x = ov[0]; o.y = ov[1]; o.z = ov[2]; o.w = ov[3];
  *(uint4*)(r + l * 8) = o;
}

// ---------------- layernorm (rows of 512, f32) ----------------

__global__ __launch_bounds__(256) void ln_rows(const float* __restrict__ X, const float* __restrict__ g,
                                               const float* __restrict__ be, float* __restrict__ out){
  int row = blockIdx.x * 4 + (threadIdx.x >> 6);
  int l = threadIdx.x & 63;
  const floatx4* p = (const floatx4*)(X + (size_t)row * 512);
  floatx4 aa = p[l * 2], bb = p[l * 2 + 1];
  float v[8];
  #pragma unroll
  for (int i = 0; i < 4; i++){ v[i] = aa[i]; v[4 + i] = bb[i]; }
  float s = 0.f, s2 = 0.f;
  #pragma unroll
  for (int i = 0; i < 8; i++){ s += v[i]; s2 += v[i] * v[i]; }
  for (int m = 1; m < 64; m <<= 1){ s += __shfl_xor(s, m, 64); s2 += __shfl_xor(s2, m, 64); }
  float mu = s * (1.f / 512.f);
  float var = s2 * (1.f / 512.f) - mu * mu;
  float rs = rsqrtf(var + 1e-5f);
  int c0 = l * 8;
  float* orow = out + (size_t)row * 512;
  #pragma unroll
  for (int i = 0; i < 8; i++)
    orow[c0 + i] = (v[i] - mu) * rs * g[c0 + i] + be[c0 + i];
}

// ---------------- launch ----------------

extern "C" void kernel_launch(void* const* d_in, const int* in_sizes, int n_in,
                              void* d_out, int out_size, void* d_ws, size_t ws_size,
                              hipStream_t stream){
  (void)in_sizes; (void)n_in; (void)out_size; (void)ws_size;
  const float* x    = (const float*)d_in[0];
  const float* gw   = (const float*)d_in[1];
  const float* Wf   = (const float*)d_in[2];
  const float* bWf  = (const float*)d_in[3];
  const float* Uf   = (const float*)d_in[4];
  const float* bUf  = (const float*)d_in[5];
  const float* Wb   = (const float*)d_in[6];
  const float* bWb  = (const float*)d_in[7];
  const float* Ub   = (const float*)d_in[8];
  const float* bUb  = (const float*)d_in[9];
  const float* inw  = (const float*)d_in[10];
  const float* inb  = (const float*)d_in[11];
  const float* outw = (const float*)d_in[12];
  const float* outb = (const float*)d_in[13];
  const float* gam  = (const float*)d_in[14];
  const float* bet  = (const float*)d_in[15];
  char* ws = (char*)d_ws;

  size_t o = 0;
  auto take = [&](size_t bytes){ size_t r = o; o += (bytes + 255) & ~(size_t)255; return r; };
  size_t o_xb   = take(16384ULL * 256 * 2);
  size_t o_wt   = take(2560ULL * 256 * 2);
  size_t o_bias = take(2560ULL * 4);
  size_t o_inw  = take(1536ULL * 512 * 2);
  size_t o_outw = take(512ULL * 512 * 2);
  size_t o_ufr  = take(655360);                 // i8 U frags
  size_t o_cs   = take(2ULL * 8 * 10 * 16 * 4); // col scales
  size_t o_dwp  = take(4ULL * 512 * 512 * 16);  // repacked dw (per-lane floatx4)
  size_t o_hcp  = take(8ULL * 512 * 512 * 8);   // packed f16 h (u64/lane)
  size_t o_hcat = take(16384ULL * 512 * 2);
  size_t o_xg   = take(16384ULL * 2560 * 2);    // xgp (exact fit); later qkv (base) + attno (+48MB)
  size_t o_vt   = take(128ULL * 128 * 512 * 2);
  size_t o_S    = take(128ULL * 512 * 512 * 2); // scores; later preln (f32)
  size_t o_qkv  = o_xg;
  size_t o_attn = o_xg + 16384ULL * 1536 * 2;
  size_t o_xgp  = o_xg;                         // 8*512*5*512*8 = 83886080 == o_xg size
  size_t o_pre  = o_S;

  u16* xb     = (u16*)(ws + o_xb);
  u16* Wt     = (u16*)(ws + o_wt);
  float* bWU  = (float*)(ws + o_bias);
  u16* inwb   = (u16*)(ws + o_inw);
  u16* outwb  = (u16*)(ws + o_outw);
  signed char* ufr = (signed char*)(ws + o_ufr);
  float* cs   = (float*)(ws + o_cs);
  floatx4* dwp = (floatx4*)(ws + o_dwp);
  u64* hcp    = (u64*)(ws + o_hcp);
  u16* hcat   = (u16*)(ws + o_hcat);
  u64* xgp    = (u64*)(ws + o_xgp);
  u16* qkv    = (u16*)(ws + o_qkv);
  u16* attn   = (u16*)(ws + o_attn);
  u16* Vt     = (u16*)(ws + o_vt);
  u16* S      = (u16*)(ws + o_S);
  float* pre  = (float*)(ws + o_pre);

  conv_bf16_k<<<4096, 256, 0, stream>>>(x, xb, 16384 * 256);
  conv_bf16_k<<<1024, 256, 0, stream>>>(inw, inwb, 1536 * 512);
  conv_bf16_k<<<512, 256, 0, stream>>>(outw, outwb, 512 * 512);
  prep_wt_k<<<2560, 256, 0, stream>>>(Wf, Wb, bWf, bWb, bUf, bUb, Wt, bWU);
  prep_uq<<<2560, 256, 0, stream>>>(Uf, Ub, ufr, cs);
  repack_dw6<<<2048, 512, 0, stream>>>(gw, dwp);

  // xg = (x @ Wt^T)*log2e + (bW+bU)*log2e, written DIRECTLY in per-lane packed layout
  gemm_bt<3><<<dim3(2560, 1), 256, 0, stream>>>(xb, Wt, (void*)xgp, bWU,
      16384, 2560, 256, 256, 256, 2560, 0, 0, 0, 0, 0, 0, 1, LOG2E);

  lstm_rec14<<<8, 512, 0, stream>>>(xgp, dwp, ufr, cs, hcp);

  hcat_un6<<<16384, 256, 0, stream>>>((const u16*)hcp, hcat);

  // qkv = hcat @ in_proj_w^T + b, bf16, [16384][1536]  (overwrites xgp region)
  gemm_bt<1><<<dim3(1536, 1), 256, 0, stream>>>(hcat, inwb, (void*)qkv, inb,
      16384, 1536, 512, 512, 512, 1536, 0, 0, 0, 0, 0, 0, 1, 1.f);

  transpose_v_k<<<dim3(128, 16, 4), dim3(32, 8), 0, stream>>>(qkv, Vt);

  // scores: per (b,h): Q[512,128] @ K^T -> S bf16 [bh][512][512], scaled
  gemm_bt<1><<<dim3(16, 128), 256, 0, stream>>>(qkv, qkv + 512, (void*)S, nullptr,
      512, 512, 128, 1536, 1536, 512,
      786432LL, 128LL, 786432LL, 128LL, 1048576LL, 262144LL, 4, 0.08838834764831845f);

  softmax_rows<<<16384, 256, 0, stream>>>(S);

  // PV: P[512,512] @ Vt^T -> attno[b][t][h*128+d] bf16
  gemm_bt<1><<<dim3(4, 128), 256, 0, stream>>>(S, Vt, (void*)attn, nullptr,
      512, 128, 512, 512, 512, 512,
      1048576LL, 262144LL, 262144LL, 65536LL, 262144LL, 128LL, 4, 1.f);

  // out proj: attno @ out_w^T + b -> preln f32
  gemm_bt<0><<<dim3(512, 1), 256, 0, stream>>>(attn, outwb, (void*)pre, outb,
      16384, 512, 512, 512, 512, 512, 0, 0, 0, 0, 0, 0, 1, 1.f);

  ln_rows<<<4096, 256, 0, stream>>>(pre, gam, bet, (float*)d_out);
}